// Round 2
// baseline (32.154 us; speedup 1.0000x reference)
//
#include <hip/hip_runtime.h>
#include <math.h>

#define N_PTS 4096
#define FLOATS_PER_BATCH (N_PTS * 3)          // 12288
#define BLK 256
#define PTS_PER_THREAD (N_PTS / BLK)          // 16
#define STATS 17

struct __align__(4) f3 { float x, y, z; };

__device__ inline double wave_reduce_sum(double v) {
    #pragma unroll
    for (int off = 32; off > 0; off >>= 1) v += __shfl_xor(v, off, 64);
    return v;
}

// Kernel 1: per-batch sufficient statistics.
// ws[b*17 + {0..2}] = sum pred, {3..5} = sum true, {6} = sum ||pred||^2,
// {7} = sum ||true||^2, {8..16} = sum pred_i * true_j (row-major 3x3)
__global__ __launch_bounds__(BLK) void kabsch_reduce(const float* __restrict__ pred,
                                                     const float* __restrict__ tru,
                                                     double* __restrict__ ws) {
    const int b = blockIdx.x;
    const int tid = threadIdx.x;
    const f3* pb = reinterpret_cast<const f3*>(pred + (size_t)b * FLOATS_PER_BATCH);
    const f3* tb = reinterpret_cast<const f3*>(tru + (size_t)b * FLOATS_PER_BATCH);

    double sp0 = 0, sp1 = 0, sp2 = 0, st0 = 0, st1 = 0, st2 = 0, spp = 0, stt = 0;
    double M00 = 0, M01 = 0, M02 = 0, M10 = 0, M11 = 0, M12 = 0, M20 = 0, M21 = 0, M22 = 0;

    #pragma unroll
    for (int c = 0; c < PTS_PER_THREAD; ++c) {
        const int n = c * BLK + tid;          // lane-adjacent -> coalesced 12B/lane
        f3 p = pb[n];
        f3 t = tb[n];
        double px = (double)p.x, py = (double)p.y, pz = (double)p.z;
        double tx = (double)t.x, ty = (double)t.y, tz = (double)t.z;
        sp0 += px; sp1 += py; sp2 += pz;
        st0 += tx; st1 += ty; st2 += tz;
        spp = fma(px, px, fma(py, py, fma(pz, pz, spp)));
        stt = fma(tx, tx, fma(ty, ty, fma(tz, tz, stt)));
        M00 = fma(px, tx, M00); M01 = fma(px, ty, M01); M02 = fma(px, tz, M02);
        M10 = fma(py, tx, M10); M11 = fma(py, ty, M11); M12 = fma(py, tz, M12);
        M20 = fma(pz, tx, M20); M21 = fma(pz, ty, M21); M22 = fma(pz, tz, M22);
    }

    double vals[STATS] = {sp0, sp1, sp2, st0, st1, st2, spp, stt,
                          M00, M01, M02, M10, M11, M12, M20, M21, M22};
    __shared__ double red[BLK / 64][STATS];
    const int lane = tid & 63, wid = tid >> 6;
    #pragma unroll
    for (int i = 0; i < STATS; ++i) {
        double r = wave_reduce_sum(vals[i]);
        if (lane == 0) red[wid][i] = r;
    }
    __syncthreads();
    if (tid < STATS) {
        double t = 0;
        #pragma unroll
        for (int w = 0; w < BLK / 64; ++w) t += red[w][tid];
        ws[(size_t)b * STATS + tid] = t;
    }
}

// Kernel 2: per-batch 3x3 closed-form singular values + RMSD, mean over B.
__global__ __launch_bounds__(1024) void kabsch_finalize(const double* __restrict__ ws,
                                                        float* __restrict__ out, int B) {
    const int tid = threadIdx.x;
    double rmsd = 0.0;
    if (tid < B) {
        const double* w = ws + (size_t)tid * STATS;
        const double invN = 1.0 / (double)N_PTS;
        double sp[3] = {w[0], w[1], w[2]};
        double st[3] = {w[3], w[4], w[5]};
        double spp = w[6], stt = w[7];
        double A[3][3];
        #pragma unroll
        for (int i = 0; i < 3; ++i)
            #pragma unroll
            for (int j = 0; j < 3; ++j)
                A[i][j] = w[8 + i * 3 + j] - sp[i] * st[j] * invN;
        double Sp = spp - (sp[0] * sp[0] + sp[1] * sp[1] + sp[2] * sp[2]) * invN;
        double St = stt - (st[0] * st[0] + st[1] * st[1] + st[2] * st[2]) * invN;

        double detA = A[0][0] * (A[1][1] * A[2][2] - A[1][2] * A[2][1])
                    - A[0][1] * (A[1][0] * A[2][2] - A[1][2] * A[2][0])
                    + A[0][2] * (A[1][0] * A[2][1] - A[1][1] * A[2][0]);

        // G = A^T A (symmetric, PSD)
        double G00 = A[0][0]*A[0][0] + A[1][0]*A[1][0] + A[2][0]*A[2][0];
        double G11 = A[0][1]*A[0][1] + A[1][1]*A[1][1] + A[2][1]*A[2][1];
        double G22 = A[0][2]*A[0][2] + A[1][2]*A[1][2] + A[2][2]*A[2][2];
        double G01 = A[0][0]*A[0][1] + A[1][0]*A[1][1] + A[2][0]*A[2][1];
        double G02 = A[0][0]*A[0][2] + A[1][0]*A[1][2] + A[2][0]*A[2][2];
        double G12 = A[0][1]*A[0][2] + A[1][1]*A[1][2] + A[2][1]*A[2][2];

        // Closed-form symmetric 3x3 eigenvalues (descending e1 >= e2 >= e3).
        double q = (G00 + G11 + G22) / 3.0;
        double p1 = G01 * G01 + G02 * G02 + G12 * G12;
        double b00 = G00 - q, b11 = G11 - q, b22 = G22 - q;
        double p2 = b00 * b00 + b11 * b11 + b22 * b22 + 2.0 * p1;
        double p = sqrt(p2 / 6.0);
        double e1, e2, e3;
        if (p > 1e-300 + 1e-14 * fabs(q)) {
            double ip = 1.0 / p;
            double C00 = b00 * ip, C11 = b11 * ip, C22 = b22 * ip;
            double C01 = G01 * ip, C02 = G02 * ip, C12 = G12 * ip;
            double r = 0.5 * (C00 * (C11 * C22 - C12 * C12)
                            - C01 * (C01 * C22 - C12 * C02)
                            + C02 * (C01 * C12 - C11 * C02));
            r = fmin(1.0, fmax(-1.0, r));
            double phi = acos(r) / 3.0;
            e1 = q + 2.0 * p * cos(phi);
            e3 = q + 2.0 * p * cos(phi + 2.0943951023931953);  // + 2*pi/3
            e2 = 3.0 * q - e1 - e3;
        } else {
            e1 = e2 = e3 = q;
        }
        double s1 = sqrt(fmax(e1, 0.0));
        double s2 = sqrt(fmax(e2, 0.0));
        double s3 = sqrt(fmax(e3, 0.0));  // smallest singular value
        double d = (detA < 0.0) ? -1.0 : 1.0;
        double tr = s1 + s2 + d * s3;
        double msd = (Sp + St - 2.0 * tr) * invN;
        rmsd = sqrt(fmax(msd, 0.0));
    }

    rmsd = wave_reduce_sum(rmsd);
    __shared__ double red[16];
    const int lane = tid & 63, wid = tid >> 6;
    if (lane == 0) red[wid] = rmsd;
    __syncthreads();
    if (tid == 0) {
        double tot = 0.0;
        #pragma unroll
        for (int w = 0; w < 16; ++w) tot += red[w];
        out[0] = (float)(tot / (double)B);
    }
}

extern "C" void kernel_launch(void* const* d_in, const int* in_sizes, int n_in,
                              void* d_out, int out_size, void* d_ws, size_t ws_size,
                              hipStream_t stream) {
    const float* pred = (const float*)d_in[0];
    const float* tru  = (const float*)d_in[1];
    float* out = (float*)d_out;
    double* ws = (double*)d_ws;
    const int B = in_sizes[0] / FLOATS_PER_BATCH;  // 1024

    kabsch_reduce<<<dim3(B), dim3(BLK), 0, stream>>>(pred, tru, ws);
    kabsch_finalize<<<dim3(1), dim3(1024), 0, stream>>>(ws, out, B);
}

// Round 3
// 29.908 us; speedup vs baseline: 1.0751x; 1.0751x over previous
//
#include <hip/hip_runtime.h>
#include <math.h>

#define N_PTS 4096
#define FLOATS_PER_BATCH (N_PTS * 3)          // 12288
#define BLK 256
#define SPLIT 2                                // blocks per batch
#define GROUPS 2                               // 3-float4 groups per thread
#define STATS 17

__device__ inline float wave_reduce_sum_f32(float v) {
    #pragma unroll
    for (int off = 32; off > 0; off >>= 1) v += __shfl_xor(v, off, 64);
    return v;
}

__device__ inline double wave_reduce_sum_f64(double v) {
    #pragma unroll
    for (int off = 32; off > 0; off >>= 1) v += __shfl_xor(v, off, 64);
    return v;
}

// Kernel 1: per-(batch, half) sufficient statistics in f32.
// ws[(b*SPLIT+h)*17 + {0..2}] = sum pred, {3..5} = sum true, {6} = sum ||pred||^2,
// {7} = sum ||true||^2, {8..16} = sum pred_i * true_j (row-major 3x3)
__global__ __launch_bounds__(BLK) void kabsch_reduce(const float* __restrict__ pred,
                                                     const float* __restrict__ tru,
                                                     float* __restrict__ ws) {
    const int bid = blockIdx.x;
    const int b = bid / SPLIT, half = bid % SPLIT;
    const int tid = threadIdx.x;
    // Each block covers 2048 points = 1536 float4s of each array.
    const float4* P = reinterpret_cast<const float4*>(pred) + (size_t)b * 3072 + (size_t)half * 1536;
    const float4* T = reinterpret_cast<const float4*>(tru)  + (size_t)b * 3072 + (size_t)half * 1536;

    // Issue ALL loads up front: 12 dwordx4 in flight per thread.
    float4 qp[GROUPS][3], qt[GROUPS][3];
    #pragma unroll
    for (int c = 0; c < GROUPS; ++c) {
        const int g = c * BLK + tid;           // 0..511, lane-adjacent
        qp[c][0] = P[g * 3 + 0]; qp[c][1] = P[g * 3 + 1]; qp[c][2] = P[g * 3 + 2];
        qt[c][0] = T[g * 3 + 0]; qt[c][1] = T[g * 3 + 1]; qt[c][2] = T[g * 3 + 2];
    }

    float a[STATS];
    #pragma unroll
    for (int i = 0; i < STATS; ++i) a[i] = 0.0f;

#define ACC(px, py, pz, tx, ty, tz) do {                                        \
        a[0] += (px); a[1] += (py); a[2] += (pz);                               \
        a[3] += (tx); a[4] += (ty); a[5] += (tz);                               \
        a[6] = fmaf((px),(px), fmaf((py),(py), fmaf((pz),(pz), a[6])));         \
        a[7] = fmaf((tx),(tx), fmaf((ty),(ty), fmaf((tz),(tz), a[7])));         \
        a[8]  = fmaf((px),(tx), a[8]);  a[9]  = fmaf((px),(ty), a[9]);          \
        a[10] = fmaf((px),(tz), a[10]); a[11] = fmaf((py),(tx), a[11]);         \
        a[12] = fmaf((py),(ty), a[12]); a[13] = fmaf((py),(tz), a[13]);         \
        a[14] = fmaf((pz),(tx), a[14]); a[15] = fmaf((pz),(ty), a[15]);         \
        a[16] = fmaf((pz),(tz), a[16]);                                         \
    } while (0)

    #pragma unroll
    for (int c = 0; c < GROUPS; ++c) {
        float4 p0 = qp[c][0], p1 = qp[c][1], p2 = qp[c][2];
        float4 t0 = qt[c][0], t1 = qt[c][1], t2 = qt[c][2];
        ACC(p0.x, p0.y, p0.z, t0.x, t0.y, t0.z);
        ACC(p0.w, p1.x, p1.y, t0.w, t1.x, t1.y);
        ACC(p1.z, p1.w, p2.x, t1.z, t1.w, t2.x);
        ACC(p2.y, p2.z, p2.w, t2.y, t2.z, t2.w);
    }
#undef ACC

    __shared__ float red[BLK / 64][STATS + 1];
    const int lane = tid & 63, wid = tid >> 6;
    #pragma unroll
    for (int i = 0; i < STATS; ++i) {
        float r = wave_reduce_sum_f32(a[i]);
        if (lane == 0) red[wid][i] = r;
    }
    __syncthreads();
    if (tid < STATS) {
        float t = 0.0f;
        #pragma unroll
        for (int w = 0; w < BLK / 64; ++w) t += red[w][tid];
        ws[(size_t)bid * STATS + tid] = t;
    }
}

// Kernel 2: per-batch 3x3 closed-form singular values + RMSD (f64), mean over B.
__global__ __launch_bounds__(1024) void kabsch_finalize(const float* __restrict__ ws,
                                                        float* __restrict__ out, int B) {
    const int tid = threadIdx.x;
    double rmsd = 0.0;
    if (tid < B) {
        double w[STATS];
        const float* w0 = ws + (size_t)(tid * SPLIT) * STATS;
        #pragma unroll
        for (int i = 0; i < STATS; ++i) {
            double s = 0.0;
            #pragma unroll
            for (int h = 0; h < SPLIT; ++h) s += (double)w0[h * STATS + i];
            w[i] = s;
        }
        const double invN = 1.0 / (double)N_PTS;
        double sp[3] = {w[0], w[1], w[2]};
        double st[3] = {w[3], w[4], w[5]};
        double spp = w[6], stt = w[7];
        double A[3][3];
        #pragma unroll
        for (int i = 0; i < 3; ++i)
            #pragma unroll
            for (int j = 0; j < 3; ++j)
                A[i][j] = w[8 + i * 3 + j] - sp[i] * st[j] * invN;
        double Sp = spp - (sp[0] * sp[0] + sp[1] * sp[1] + sp[2] * sp[2]) * invN;
        double St = stt - (st[0] * st[0] + st[1] * st[1] + st[2] * st[2]) * invN;

        double detA = A[0][0] * (A[1][1] * A[2][2] - A[1][2] * A[2][1])
                    - A[0][1] * (A[1][0] * A[2][2] - A[1][2] * A[2][0])
                    + A[0][2] * (A[1][0] * A[2][1] - A[1][1] * A[2][0]);

        double G00 = A[0][0]*A[0][0] + A[1][0]*A[1][0] + A[2][0]*A[2][0];
        double G11 = A[0][1]*A[0][1] + A[1][1]*A[1][1] + A[2][1]*A[2][1];
        double G22 = A[0][2]*A[0][2] + A[1][2]*A[1][2] + A[2][2]*A[2][2];
        double G01 = A[0][0]*A[0][1] + A[1][0]*A[1][1] + A[2][0]*A[2][1];
        double G02 = A[0][0]*A[0][2] + A[1][0]*A[1][2] + A[2][0]*A[2][2];
        double G12 = A[0][1]*A[0][2] + A[1][1]*A[1][2] + A[2][1]*A[2][2];

        double q = (G00 + G11 + G22) / 3.0;
        double p1 = G01 * G01 + G02 * G02 + G12 * G12;
        double b00 = G00 - q, b11 = G11 - q, b22 = G22 - q;
        double p2 = b00 * b00 + b11 * b11 + b22 * b22 + 2.0 * p1;
        double p = sqrt(p2 / 6.0);
        double e1, e2, e3;
        if (p > 1e-300 + 1e-14 * fabs(q)) {
            double ip = 1.0 / p;
            double C00 = b00 * ip, C11 = b11 * ip, C22 = b22 * ip;
            double C01 = G01 * ip, C02 = G02 * ip, C12 = G12 * ip;
            double r = 0.5 * (C00 * (C11 * C22 - C12 * C12)
                            - C01 * (C01 * C22 - C12 * C02)
                            + C02 * (C01 * C12 - C11 * C02));
            r = fmin(1.0, fmax(-1.0, r));
            double phi = acos(r) / 3.0;
            e1 = q + 2.0 * p * cos(phi);
            e3 = q + 2.0 * p * cos(phi + 2.0943951023931953);  // + 2*pi/3
            e2 = 3.0 * q - e1 - e3;
        } else {
            e1 = e2 = e3 = q;
        }
        double s1 = sqrt(fmax(e1, 0.0));
        double s2 = sqrt(fmax(e2, 0.0));
        double s3 = sqrt(fmax(e3, 0.0));
        double d = (detA < 0.0) ? -1.0 : 1.0;
        double tr = s1 + s2 + d * s3;
        double msd = (Sp + St - 2.0 * tr) * invN;
        rmsd = sqrt(fmax(msd, 0.0));
    }

    rmsd = wave_reduce_sum_f64(rmsd);
    __shared__ double red[16];
    const int lane = tid & 63, wid = tid >> 6;
    if (lane == 0) red[wid] = rmsd;
    __syncthreads();
    if (tid == 0) {
        double tot = 0.0;
        #pragma unroll
        for (int w = 0; w < 16; ++w) tot += red[w];
        out[0] = (float)(tot / (double)B);
    }
}

extern "C" void kernel_launch(void* const* d_in, const int* in_sizes, int n_in,
                              void* d_out, int out_size, void* d_ws, size_t ws_size,
                              hipStream_t stream) {
    const float* pred = (const float*)d_in[0];
    const float* tru  = (const float*)d_in[1];
    float* out = (float*)d_out;
    float* ws = (float*)d_ws;
    const int B = in_sizes[0] / FLOATS_PER_BATCH;  // 1024

    kabsch_reduce<<<dim3(B * SPLIT), dim3(BLK), 0, stream>>>(pred, tru, ws);
    kabsch_finalize<<<dim3(1), dim3(1024), 0, stream>>>(ws, out, B);
}

// Round 4
// 28.001 us; speedup vs baseline: 1.1483x; 1.0681x over previous
//
#include <hip/hip_runtime.h>
#include <math.h>

#define N_PTS 4096
#define FLOATS_PER_BATCH (N_PTS * 3)          // 12288
#define BLK 256
#define SPLIT 2                                // blocks per batch
#define GROUPS 2                               // 3-float4 groups per thread
#define STATS 17

__device__ inline float wave_reduce_sum_f32(float v) {
    #pragma unroll
    for (int off = 32; off > 0; off >>= 1) v += __shfl_xor(v, off, 64);
    return v;
}

// Kernel 1: per-(batch, half) sufficient statistics in f32.
// ws[(b*SPLIT+h)*17 + {0..2}] = sum pred, {3..5} = sum true, {6} = sum ||pred||^2,
// {7} = sum ||true||^2, {8..16} = sum pred_i * true_j (row-major 3x3)
__global__ __launch_bounds__(BLK) void kabsch_reduce(const float* __restrict__ pred,
                                                     const float* __restrict__ tru,
                                                     float* __restrict__ ws) {
    const int bid = blockIdx.x;
    const int b = bid / SPLIT, half = bid % SPLIT;
    const int tid = threadIdx.x;
    // Each block covers 2048 points = 1536 float4s of each array.
    const float4* P = reinterpret_cast<const float4*>(pred) + (size_t)b * 3072 + (size_t)half * 1536;
    const float4* T = reinterpret_cast<const float4*>(tru)  + (size_t)b * 3072 + (size_t)half * 1536;

    // Issue ALL loads up front: 12 dwordx4 in flight per thread.
    float4 qp[GROUPS][3], qt[GROUPS][3];
    #pragma unroll
    for (int c = 0; c < GROUPS; ++c) {
        const int g = c * BLK + tid;           // 0..511, lane-adjacent
        qp[c][0] = P[g * 3 + 0]; qp[c][1] = P[g * 3 + 1]; qp[c][2] = P[g * 3 + 2];
        qt[c][0] = T[g * 3 + 0]; qt[c][1] = T[g * 3 + 1]; qt[c][2] = T[g * 3 + 2];
    }

    float a[STATS];
    #pragma unroll
    for (int i = 0; i < STATS; ++i) a[i] = 0.0f;

#define ACC(px, py, pz, tx, ty, tz) do {                                        \
        a[0] += (px); a[1] += (py); a[2] += (pz);                               \
        a[3] += (tx); a[4] += (ty); a[5] += (tz);                               \
        a[6] = fmaf((px),(px), fmaf((py),(py), fmaf((pz),(pz), a[6])));         \
        a[7] = fmaf((tx),(tx), fmaf((ty),(ty), fmaf((tz),(tz), a[7])));         \
        a[8]  = fmaf((px),(tx), a[8]);  a[9]  = fmaf((px),(ty), a[9]);          \
        a[10] = fmaf((px),(tz), a[10]); a[11] = fmaf((py),(tx), a[11]);         \
        a[12] = fmaf((py),(ty), a[12]); a[13] = fmaf((py),(tz), a[13]);         \
        a[14] = fmaf((pz),(tx), a[14]); a[15] = fmaf((pz),(ty), a[15]);         \
        a[16] = fmaf((pz),(tz), a[16]);                                         \
    } while (0)

    #pragma unroll
    for (int c = 0; c < GROUPS; ++c) {
        float4 p0 = qp[c][0], p1 = qp[c][1], p2 = qp[c][2];
        float4 t0 = qt[c][0], t1 = qt[c][1], t2 = qt[c][2];
        ACC(p0.x, p0.y, p0.z, t0.x, t0.y, t0.z);
        ACC(p0.w, p1.x, p1.y, t0.w, t1.x, t1.y);
        ACC(p1.z, p1.w, p2.x, t1.z, t1.w, t2.x);
        ACC(p2.y, p2.z, p2.w, t2.y, t2.z, t2.w);
    }
#undef ACC

    __shared__ float red[BLK / 64][STATS + 1];
    const int lane = tid & 63, wid = tid >> 6;
    #pragma unroll
    for (int i = 0; i < STATS; ++i) {
        float r = wave_reduce_sum_f32(a[i]);
        if (lane == 0) red[wid][i] = r;
    }
    __syncthreads();
    if (tid < STATS) {
        float t = 0.0f;
        #pragma unroll
        for (int w = 0; w < BLK / 64; ++w) t += red[w][tid];
        ws[(size_t)bid * STATS + tid] = t;
    }
}

// Kernel 2: per-batch 3x3 closed-form singular values + RMSD, all f32, mean over B.
__global__ __launch_bounds__(1024) void kabsch_finalize(const float* __restrict__ ws,
                                                        float* __restrict__ out, int B) {
    const int tid = threadIdx.x;
    float rmsd = 0.0f;
    if (tid < B) {
        float w[STATS];
        const float* w0 = ws + (size_t)(tid * SPLIT) * STATS;
        #pragma unroll
        for (int i = 0; i < STATS; ++i) {
            float s = 0.0f;
            #pragma unroll
            for (int h = 0; h < SPLIT; ++h) s += w0[h * STATS + i];
            w[i] = s;
        }
        const float invN = 1.0f / (float)N_PTS;
        float sp[3] = {w[0], w[1], w[2]};
        float st[3] = {w[3], w[4], w[5]};
        float A[3][3];
        #pragma unroll
        for (int i = 0; i < 3; ++i)
            #pragma unroll
            for (int j = 0; j < 3; ++j)
                A[i][j] = w[8 + i * 3 + j] - sp[i] * st[j] * invN;
        float Sp = w[6] - (sp[0] * sp[0] + sp[1] * sp[1] + sp[2] * sp[2]) * invN;
        float St = w[7] - (st[0] * st[0] + st[1] * st[1] + st[2] * st[2]) * invN;

        float detA = A[0][0] * (A[1][1] * A[2][2] - A[1][2] * A[2][1])
                   - A[0][1] * (A[1][0] * A[2][2] - A[1][2] * A[2][0])
                   + A[0][2] * (A[1][0] * A[2][1] - A[1][1] * A[2][0]);

        // G = A^T A (symmetric, PSD)
        float G00 = A[0][0]*A[0][0] + A[1][0]*A[1][0] + A[2][0]*A[2][0];
        float G11 = A[0][1]*A[0][1] + A[1][1]*A[1][1] + A[2][1]*A[2][1];
        float G22 = A[0][2]*A[0][2] + A[1][2]*A[1][2] + A[2][2]*A[2][2];
        float G01 = A[0][0]*A[0][1] + A[1][0]*A[1][1] + A[2][0]*A[2][1];
        float G02 = A[0][0]*A[0][2] + A[1][0]*A[1][2] + A[2][0]*A[2][2];
        float G12 = A[0][1]*A[0][2] + A[1][1]*A[1][2] + A[2][1]*A[2][2];

        // Closed-form symmetric 3x3 eigenvalues (descending e1 >= e2 >= e3).
        float q = (G00 + G11 + G22) * (1.0f / 3.0f);
        float p1 = G01 * G01 + G02 * G02 + G12 * G12;
        float b00 = G00 - q, b11 = G11 - q, b22 = G22 - q;
        float p2 = b00 * b00 + b11 * b11 + b22 * b22 + 2.0f * p1;
        float p = sqrtf(p2 * (1.0f / 6.0f));
        float e1, e2, e3;
        if (p > 1e-30f + 1e-6f * fabsf(q)) {
            float ip = 1.0f / p;
            float C00 = b00 * ip, C11 = b11 * ip, C22 = b22 * ip;
            float C01 = G01 * ip, C02 = G02 * ip, C12 = G12 * ip;
            float r = 0.5f * (C00 * (C11 * C22 - C12 * C12)
                            - C01 * (C01 * C22 - C12 * C02)
                            + C02 * (C01 * C12 - C11 * C02));
            r = fminf(1.0f, fmaxf(-1.0f, r));
            float phi = acosf(r) * (1.0f / 3.0f);
            e1 = q + 2.0f * p * __cosf(phi);
            e3 = q + 2.0f * p * __cosf(phi + 2.0943951023931953f);  // + 2*pi/3
            e2 = 3.0f * q - e1 - e3;
        } else {
            e1 = e2 = e3 = q;
        }
        float s1 = sqrtf(fmaxf(e1, 0.0f));
        float s2 = sqrtf(fmaxf(e2, 0.0f));
        float s3 = sqrtf(fmaxf(e3, 0.0f));  // smallest singular value
        float d = (detA < 0.0f) ? -1.0f : 1.0f;
        float tr = s1 + s2 + d * s3;
        float msd = (Sp + St - 2.0f * tr) * invN;
        rmsd = sqrtf(fmaxf(msd, 0.0f));
    }

    rmsd = wave_reduce_sum_f32(rmsd);
    __shared__ float red[16];
    const int lane = tid & 63, wid = tid >> 6;
    if (lane == 0) red[wid] = rmsd;
    __syncthreads();
    if (tid == 0) {
        float tot = 0.0f;
        #pragma unroll
        for (int w = 0; w < 16; ++w) tot += red[w];
        out[0] = tot / (float)B;
    }
}

extern "C" void kernel_launch(void* const* d_in, const int* in_sizes, int n_in,
                              void* d_out, int out_size, void* d_ws, size_t ws_size,
                              hipStream_t stream) {
    const float* pred = (const float*)d_in[0];
    const float* tru  = (const float*)d_in[1];
    float* out = (float*)d_out;
    float* ws = (float*)d_ws;
    const int B = in_sizes[0] / FLOATS_PER_BATCH;  // 1024

    kabsch_reduce<<<dim3(B * SPLIT), dim3(BLK), 0, stream>>>(pred, tru, ws);
    kabsch_finalize<<<dim3(1), dim3(1024), 0, stream>>>(ws, out, B);
}